// Round 18
// baseline (102.680 us; speedup 1.0000x reference)
//
#include <hip/hip_runtime.h>
#include <math.h>

#define NN 512
#define CC 32
#define EPSF 1e-8f
#define WS 40   // shorts per LDS weight row
#define GS 12   // floats per geom row (48 B)

typedef __attribute__((ext_vector_type(8))) short bf16x8;
typedef __attribute__((ext_vector_type(4))) float f32x4;
typedef __attribute__((ext_vector_type(16))) float f32x16;

// fp32 -> bf16 bits, round-to-nearest-even (staging only)
__device__ __forceinline__ short f2bf(float f) {
    unsigned u = __float_as_uint(f);
    u += 0x7fffu + ((u >> 16) & 1u);
    return (short)(u >> 16);
}

// packed f32x2 -> bf16x2 (RTNE), 1 VALU op
__device__ __forceinline__ unsigned cvtpk(float lo, float hi) {
    unsigned r;
    asm("v_cvt_pk_bf16_f32 %0, %1, %2" : "=v"(r) : "v"(lo), "v"(hi));
    return r;
}

// Stage filter F's weights as bf16 into LDS.  w1 plain [n][k];
// w2 with n-axis permuted (k2) so layer-2's A-frag is the packed layer-1 D regs.
#define STAGE_F(F, W1P, W2P)                                                   \
    {                                                                          \
        wlds[(((F) * 2 + 0) * 32 + n0) * WS + k0]      = f2bf((W1P)[tid]);     \
        wlds[(((F) * 2 + 0) * 32 + n0 + 16) * WS + k0] = f2bf((W1P)[tid+512]); \
        wlds[(((F) * 2 + 1) * 32 + n0) * WS + k2]      = f2bf((W2P)[tid]);     \
        wlds[(((F) * 2 + 1) * 32 + n0 + 16) * WS + k2] = f2bf((W2P)[tid+512]); \
    }

// One radial MLP for 32 pairs x 32 channels via 4 x mfma_32x32x16 (verified r17).
#define LAYER12(F, B2V, RAD)                                                       \
    {                                                                              \
        const bf16x8 w1i0M = *(const bf16x8*)&wlds[(((F)*2+0)*32 + cc)*WS + 8*hp]; \
        const bf16x8 w1i1M = *(const bf16x8*)&wlds[(((F)*2+0)*32 + cc)*WS + 16 + 8*hp]; \
        f32x16 d1M = *(const f32x16*)&b1p[(F)*32 + hp*16];                         \
        d1M = __builtin_amdgcn_mfma_f32_32x32x16_bf16(w1i0M, rbf0F, d1M, 0, 0, 0); \
        d1M = __builtin_amdgcn_mfma_f32_32x32x16_bf16(w1i1M, rbf1F, d1M, 0, 0, 0); \
        union { bf16x8 v; unsigned u[4]; } hAM, hBM;                               \
        hAM.u[0] = cvtpk(fmaxf(d1M[0],  0.f), fmaxf(d1M[1],  0.f));                \
        hAM.u[1] = cvtpk(fmaxf(d1M[2],  0.f), fmaxf(d1M[3],  0.f));                \
        hAM.u[2] = cvtpk(fmaxf(d1M[4],  0.f), fmaxf(d1M[5],  0.f));                \
        hAM.u[3] = cvtpk(fmaxf(d1M[6],  0.f), fmaxf(d1M[7],  0.f));                \
        hBM.u[0] = cvtpk(fmaxf(d1M[8],  0.f), fmaxf(d1M[9],  0.f));                \
        hBM.u[1] = cvtpk(fmaxf(d1M[10], 0.f), fmaxf(d1M[11], 0.f));                \
        hBM.u[2] = cvtpk(fmaxf(d1M[12], 0.f), fmaxf(d1M[13], 0.f));                \
        hBM.u[3] = cvtpk(fmaxf(d1M[14], 0.f), fmaxf(d1M[15], 0.f));                \
        const bf16x8 w2i0M = *(const bf16x8*)&wlds[(((F)*2+1)*32 + cc)*WS + 8*hp]; \
        const bf16x8 w2i1M = *(const bf16x8*)&wlds[(((F)*2+1)*32 + cc)*WS + 16 + 8*hp]; \
        f32x16 rdM = { (B2V),(B2V),(B2V),(B2V),(B2V),(B2V),(B2V),(B2V),            \
                       (B2V),(B2V),(B2V),(B2V),(B2V),(B2V),(B2V),(B2V) };          \
        rdM = __builtin_amdgcn_mfma_f32_32x32x16_bf16(hAM.v, w2i0M, rdM, 0, 0, 0); \
        rdM = __builtin_amdgcn_mfma_f32_32x32x16_bf16(hBM.v, w2i1M, rdM, 0, 0, 0); \
        RAD = rdM;                                                                 \
    }

// pair offset for D reg R (pair b = gbb + POFF(R))
#define POFF(R) (((R) & 3) + 8 * ((R) >> 2))

// filter-0 (scalar): o0_s, o1_s, o2_s
#define AGG0R(R, RAD)                                                          \
    {                                                                          \
        const float sA = (RAD)[(R)];                                           \
        const float i0A = p0b[POFF(R) * 32];                                   \
        const float xA = p1b[POFF(R)*96 + 0], yA = p1b[POFF(R)*96 + 1], zA = p1b[POFF(R)*96 + 2]; \
        a0  = fmaf(sA, i0A, a0);                                               \
        a5  = fmaf(sA, xA, a5);                                                \
        a6  = fmaf(sA, yA, a6);                                                \
        a7  = fmaf(sA, zA, a7);                                                \
        a16 = fmaf(sA, p2b[POFF(R)*160 + 0], a16);                             \
        a17 = fmaf(sA, p2b[POFF(R)*160 + 1], a17);                             \
        a18 = fmaf(sA, p2b[POFF(R)*160 + 2], a18);                             \
        a19 = fmaf(sA, p2b[POFF(R)*160 + 3], a19);                             \
        a20 = fmaf(sA, p2b[POFF(R)*160 + 4], a20);                             \
    }

// filter-1 (0x1->1): o1_a
#define AGG1R(R, RAD)                                                          \
    {                                                                          \
        const f32x4 gA = *(const f32x4*)&geomall[gbb + POFF(R)][0];            \
        const float t1A = (RAD)[(R)] * p0b[POFF(R) * 32];                      \
        a2  = fmaf(t1A, gA[0], a2);                                            \
        a3  = fmaf(t1A, gA[1], a3);                                            \
        a4  = fmaf(t1A, gA[2], a4);                                            \
    }

// filter-2 (0x2->2): o2_a
#define AGG2R(R, RAD)                                                          \
    {                                                                          \
        const f32x4 gA = *(const f32x4*)&geomall[gbb + POFF(R)][0];            \
        const f32x4 gB = *(const f32x4*)&geomall[gbb + POFF(R)][4];            \
        const float t2A = (RAD)[(R)] * p0b[POFF(R) * 32];                      \
        a11 = fmaf(t2A, gA[3], a11);                                           \
        a12 = fmaf(t2A, gB[0], a12);                                           \
        a13 = fmaf(t2A, gB[1], a13);                                           \
        a14 = fmaf(t2A, gB[2], a14);                                           \
        a15 = fmaf(t2A, gB[3], a15);                                           \
    }

// filter-3 (1x1->0): o0_b
#define AGG3R(R, RAD)                                                          \
    {                                                                          \
        const f32x4 gA = *(const f32x4*)&geomall[gbb + POFF(R)][0];            \
        const float xA = p1b[POFF(R)*96 + 0], yA = p1b[POFF(R)*96 + 1], zA = p1b[POFF(R)*96 + 2]; \
        const float dtA = fmaf(gA[2], zA, fmaf(gA[1], yA, gA[0] * xA));        \
        a1  = fmaf((RAD)[(R)], dtA, a1);                                       \
    }

// filter-4 (1x1->1): o1_c (cross product)
#define AGG4R(R, RAD)                                                          \
    {                                                                          \
        const f32x4 gA = *(const f32x4*)&geomall[gbb + POFF(R)][0];            \
        const float xA = p1b[POFF(R)*96 + 0], yA = p1b[POFF(R)*96 + 1], zA = p1b[POFF(R)*96 + 2]; \
        const float cxA = fmaf(gA[1], zA, -(gA[2] * yA));                      \
        const float cyA = fmaf(gA[2], xA, -(gA[0] * zA));                      \
        const float czA = fmaf(gA[0], yA, -(gA[1] * xA));                      \
        a8  = fmaf((RAD)[(R)], cxA, a8);                                       \
        a9  = fmaf((RAD)[(R)], cyA, a9);                                       \
        a10 = fmaf((RAD)[(R)], czA, a10);                                      \
    }

#define AGG16(M, RAD) M(0,RAD) M(1,RAD) M(2,RAD) M(3,RAD) M(4,RAD) M(5,RAD)    \
                      M(6,RAD) M(7,RAD) M(8,RAD) M(9,RAD) M(10,RAD) M(11,RAD)  \
                      M(12,RAD) M(13,RAD) M(14,RAD) M(15,RAD)

#define RED(CMP, V)                                                            \
    {                                                                          \
        float vR = (V);                                                        \
        vR += __shfl_down(vR, 32);                                             \
        if (lane < 32) red[(w * 21 + (CMP)) * 32 + lane] = vR;                 \
    }

__global__ __launch_bounds__(512, 2) void tfn_mfma(
    const float* __restrict__ in0,   // [N,C,1]
    const float* __restrict__ in1,   // [N,C,3]
    const float* __restrict__ in2,   // [N,C,5]
    const float* __restrict__ rbf,   // [N,N,32]
    const float* __restrict__ rij,   // [N,N,3]
    const float* __restrict__ w1_0, const float* __restrict__ b1_0,
    const float* __restrict__ w2_0, const float* __restrict__ b2_0,
    const float* __restrict__ w1_1, const float* __restrict__ b1_1,
    const float* __restrict__ w2_1, const float* __restrict__ b2_1,
    const float* __restrict__ w1_2, const float* __restrict__ b1_2,
    const float* __restrict__ w2_2, const float* __restrict__ b2_2,
    const float* __restrict__ w1_3, const float* __restrict__ b1_3,
    const float* __restrict__ w2_3, const float* __restrict__ b2_3,
    const float* __restrict__ w1_4, const float* __restrict__ b1_4,
    const float* __restrict__ w2_4, const float* __restrict__ b2_4,
    float* __restrict__ out)
{
    const int a    = blockIdx.x;
    const int tid  = threadIdx.x;
    const int w    = tid >> 6;     // wave 0..7: owns b range [w*64, w*64+64)
    const int lane = tid & 63;
    const int cc   = lane & 31;    // layer1 row n / layer2 col c / channel
    const int hp   = lane >> 5;    // half-wave (k-half / pair sub-set)

    __shared__ short wlds[5 * 2 * 32 * WS];  // 25600 B; aliased as `red` later
    __shared__ float geomall[NN][GS];        // 24576 B: all b's geometry (mask folded)
    __shared__ float b1p[5 * 32];            // 640 B: layer-1 biases, D-reg order

    // staging indices; k2 = D-reg-order permutation for layer-2 weights
    const int n0 = tid >> 5, k0 = tid & 31;
    const int np_ = k0 & 15;
    const int k2 = (k0 >> 4) * 16 + ((np_ >> 2) & 1) * 8 + (np_ & 3) + 4 * (np_ >> 3);

    STAGE_F(0, w1_0, w2_0)
    STAGE_F(1, w1_1, w2_1)
    STAGE_F(2, w1_2, w2_2)
    STAGE_F(3, w1_3, w2_3)
    STAGE_F(4, w1_4, w2_4)

    if (tid < 32) {
        const int rr_ = tid & 15, hh_ = tid >> 4;
        const int ns_ = (rr_ & 3) + 8 * (rr_ >> 2) + 4 * hh_;
        b1p[0 * 32 + tid] = b1_0[ns_];
        b1p[1 * 32 + tid] = b1_1[ns_];
        b1p[2 * 32 + tid] = b1_2[ns_];
        b1p[3 * 32 + tid] = b1_3[ns_];
        b1p[4 * 32 + tid] = b1_4[ns_];
    }

    const size_t rowbase = (size_t)a * NN;
    const float Y2C = 0.28867513459481287f;  // 1/(2*sqrt(3))

    // ---- geometry for ALL 512 b's, one thread each ----
    {
        const float* rp = rij + (rowbase + tid) * 3;
        const float x = rp[0], y = rp[1], z = rp[2];
        const float d2 = x * x + y * y + z * z;
        const float d  = sqrtf(d2);
        const float m  = (d >= EPSF) ? 1.f : 0.f;
        const float inv = m / (d + EPSF);
        const float ir2 = m / fmaxf(d2, EPSF);
        f32x4 gA = { x * inv, y * inv, z * inv, x * y * ir2 };
        f32x4 gB = { y * z * ir2, (2.f * z * z - x * x - y * y) * (ir2 * Y2C),
                     z * x * ir2, (x * x - y * y) * (ir2 * 0.5f) };
        *(f32x4*)&geomall[tid][0] = gA;
        *(f32x4*)&geomall[tid][4] = gB;
    }

    // layer-2 bias: own channel (5 VGPR)
    const float b2v0 = b2_0[cc], b2v1 = b2_1[cc], b2v2 = b2_2[cc];
    const float b2v3 = b2_3[cc], b2v4 = b2_4[cc];
    __syncthreads();

    // 21 named scalar accumulators
    float a0 = 0.f, a1 = 0.f, a2 = 0.f, a3 = 0.f, a4 = 0.f, a5 = 0.f, a6 = 0.f;
    float a7 = 0.f, a8 = 0.f, a9 = 0.f, a10 = 0.f, a11 = 0.f, a12 = 0.f, a13 = 0.f;
    float a14 = 0.f, a15 = 0.f, a16 = 0.f, a17 = 0.f, a18 = 0.f, a19 = 0.f, a20 = 0.f;

    // rbf B-frag source: this lane's rbf row (tile 1 = +1024 floats)
    const float* rb_base = rbf + (rowbase + w * 64 + cc) * 32;
    f32x4 pA0 = *(const f32x4*)(rb_base + 8 * hp);
    f32x4 pA1 = *(const f32x4*)(rb_base + 8 * hp + 4);
    f32x4 pB0 = *(const f32x4*)(rb_base + 16 + 8 * hp);
    f32x4 pB1 = *(const f32x4*)(rb_base + 16 + 8 * hp + 4);

    #pragma unroll 1
    for (int T = 0; T < 2; ++T) {
        const int b0  = w * 64 + T * 32;
        const int gbb = b0 + 4 * hp;
        const float* p0b = in0 + gbb * CC + cc;
        const float* p1b = in1 + (gbb * CC + cc) * 3;
        const float* p2b = in2 + (gbb * CC + cc) * 5;

        union { bf16x8 v; unsigned u[4]; } r0u, r1u;
        r0u.u[0] = cvtpk(pA0[0], pA0[1]); r0u.u[1] = cvtpk(pA0[2], pA0[3]);
        r0u.u[2] = cvtpk(pA1[0], pA1[1]); r0u.u[3] = cvtpk(pA1[2], pA1[3]);
        r1u.u[0] = cvtpk(pB0[0], pB0[1]); r1u.u[1] = cvtpk(pB0[2], pB0[3]);
        r1u.u[2] = cvtpk(pB1[0], pB1[1]); r1u.u[3] = cvtpk(pB1[2], pB1[3]);
        const bf16x8 rbf0F = r0u.v;
        const bf16x8 rbf1F = r1u.v;
        if (T == 0) {   // prefetch tile 1's rbf fragments
            pA0 = *(const f32x4*)(rb_base + 1024 + 8 * hp);
            pA1 = *(const f32x4*)(rb_base + 1024 + 8 * hp + 4);
            pB0 = *(const f32x4*)(rb_base + 1024 + 16 + 8 * hp);
            pB1 = *(const f32x4*)(rb_base + 1024 + 16 + 8 * hp + 4);
        }

        // two-buffer rad interleave: L12(F+1) overlaps AGG(F); max 2 rads live
        f32x16 rA, rB;
        LAYER12(0, b2v0, rA)
        LAYER12(1, b2v1, rB)
        AGG16(AGG0R, rA)
        LAYER12(2, b2v2, rA)
        AGG16(AGG1R, rB)
        LAYER12(3, b2v3, rB)
        AGG16(AGG2R, rA)
        LAYER12(4, b2v4, rA)
        AGG16(AGG3R, rB)
        AGG16(AGG4R, rA)
    }

    // ---- reduce across half-waves, then across the 8 waves via LDS ----
    __syncthreads();                       // all waves done reading wlds
    float* red = (float*)wlds;             // [8][21][32] = 21504 B <= 25600 B
    RED(0,  a0)  RED(1,  a1)  RED(2,  a2)  RED(3,  a3)  RED(4,  a4)
    RED(5,  a5)  RED(6,  a6)  RED(7,  a7)  RED(8,  a8)  RED(9,  a9)
    RED(10, a10) RED(11, a11) RED(12, a12) RED(13, a13) RED(14, a14)
    RED(15, a15) RED(16, a16) RED(17, a17) RED(18, a18) RED(19, a19)
    RED(20, a20)
    __syncthreads();

    const int NC = NN * CC;
    for (int e = tid; e < 21 * 32; e += 512) {
        const int cmp = e >> 5, c = e & 31;
        float s = 0.f;
        #pragma unroll
        for (int g = 0; g < 8; ++g) s += red[(g * 21 + cmp) * 32 + c];
        int idx;
        if (cmp == 0)       idx = a * CC + c;                                       // o0_s
        else if (cmp == 1)  idx = NC + a * CC + c;                                  // o0_b
        else if (cmp < 5)   idx = 2 * NC + (a * CC + c) * 3 + (cmp - 2);            // o1_a
        else if (cmp < 8)   idx = 2 * NC + 3 * NC + (a * CC + c) * 3 + (cmp - 5);   // o1_s
        else if (cmp < 11)  idx = 2 * NC + 6 * NC + (a * CC + c) * 3 + (cmp - 8);   // o1_c
        else if (cmp < 16)  idx = 11 * NC + (a * CC + c) * 5 + (cmp - 11);          // o2_a
        else                idx = 11 * NC + 5 * NC + (a * CC + c) * 5 + (cmp - 16); // o2_s
        out[idx] = s;
    }
}

extern "C" void kernel_launch(void* const* d_in, const int* in_sizes, int n_in,
                              void* d_out, int out_size, void* d_ws, size_t ws_size,
                              hipStream_t stream) {
    const float* in0 = (const float*)d_in[0];
    const float* in1 = (const float*)d_in[1];
    const float* in2 = (const float*)d_in[2];
    const float* rbf = (const float*)d_in[3];
    const float* rij = (const float*)d_in[4];

    hipLaunchKernelGGL(tfn_mfma, dim3(NN), dim3(512), 0, stream,
                       in0, in1, in2, rbf, rij,
                       (const float*)d_in[5],  (const float*)d_in[6],
                       (const float*)d_in[7],  (const float*)d_in[8],
                       (const float*)d_in[9],  (const float*)d_in[10],
                       (const float*)d_in[11], (const float*)d_in[12],
                       (const float*)d_in[13], (const float*)d_in[14],
                       (const float*)d_in[15], (const float*)d_in[16],
                       (const float*)d_in[17], (const float*)d_in[18],
                       (const float*)d_in[19], (const float*)d_in[20],
                       (const float*)d_in[21], (const float*)d_in[22],
                       (const float*)d_in[23], (const float*)d_in[24],
                       (float*)d_out);
}

// Round 19
// 50.029 us; speedup vs baseline: 2.0524x; 2.0524x over previous
//
#include <hip/hip_runtime.h>
#include <math.h>

#define NN 512
#define CC 32
#define EPSF 1e-8f
#define WS 40   // shorts per LDS weight row
#define GS 12   // floats per geom row (48 B: 2-way max bank aliasing = free)
#define HB 256  // b's per half-block

typedef __attribute__((ext_vector_type(8))) short bf16x8;
typedef __attribute__((ext_vector_type(4))) float f32x4;

// fp32 -> bf16 bits, round-to-nearest-even (staging only)
__device__ __forceinline__ short f2bf(float f) {
    unsigned u = __float_as_uint(f);
    u += 0x7fffu + ((u >> 16) & 1u);
    return (short)(u >> 16);
}

// packed f32x2 -> bf16x2 (RTNE), 1 VALU op
__device__ __forceinline__ unsigned cvtpk(float lo, float hi) {
    unsigned r;
    asm("v_cvt_pk_bf16_f32 %0, %1, %2" : "=v"(r) : "v"(lo), "v"(hi));
    return r;
}

// Stage filter F's weights as bf16 into LDS (compile-time F).
// w1 plain [n][k]; w2 with k-axis permuted so layer-2's A-frag is lane-local.
#define STAGE_F(F, W1P, W2P)                                                   \
    {                                                                          \
        wlds[(((F) * 2 + 0) * 32 + n0) * WS + k0]      = f2bf((W1P)[tid]);     \
        wlds[(((F) * 2 + 0) * 32 + n0 + 16) * WS + k0] = f2bf((W1P)[tid+512]); \
        wlds[(((F) * 2 + 1) * 32 + n0) * WS + k2]      = f2bf((W2P)[tid]);     \
        wlds[(((F) * 2 + 1) * 32 + n0 + 16) * WS + k2] = f2bf((W2P)[tid+512]); \
    }

// Radial MLP, transpose-free; layer-1 bias from LDS (broadcast).
//  layer1 swapped: d = mfma(w1, rbf) -> lane(q,ln) = h[n][p=ln]
//  relu+cvt_pk packs the 8 lane-local h values -> layer-2 A-frag (w2 permuted)
//  layer2: R[rr] = rad[p=4q+rr][cw]
#define MLP3S(WOFF, BOFF, B2V, R)                                                  \
    {                                                                              \
        const bf16x8 w1loM = *(const bf16x8*)&wlds[(WOFF) + ln * WS + q * 8];      \
        const bf16x8 w1hiM = *(const bf16x8*)&wlds[(WOFF) + (16 + ln) * WS + q * 8]; \
        f32x4 d0M = *(const f32x4*)&b1lds[(BOFF) + 4 * q];                         \
        f32x4 d1M = *(const f32x4*)&b1lds[(BOFF) + 16 + 4 * q];                    \
        d0M = __builtin_amdgcn_mfma_f32_16x16x32_bf16(w1loM, rbfF, d0M, 0, 0, 0);  \
        d1M = __builtin_amdgcn_mfma_f32_16x16x32_bf16(w1hiM, rbfF, d1M, 0, 0, 0);  \
        union { bf16x8 v; unsigned u[4]; } hu;                                     \
        hu.u[0] = cvtpk(fmaxf(d0M[0], 0.f), fmaxf(d0M[1], 0.f));                   \
        hu.u[1] = cvtpk(fmaxf(d0M[2], 0.f), fmaxf(d0M[3], 0.f));                   \
        hu.u[2] = cvtpk(fmaxf(d1M[0], 0.f), fmaxf(d1M[1], 0.f));                   \
        hu.u[3] = cvtpk(fmaxf(d1M[2], 0.f), fmaxf(d1M[3], 0.f));                   \
        const bf16x8 w2M = *(const bf16x8*)&wlds[(WOFF) + (32 + ch0 + ln) * WS + q * 8]; \
        f32x4 eM = { (B2V), (B2V), (B2V), (B2V) };                                 \
        R = __builtin_amdgcn_mfma_f32_16x16x32_bf16(hu.v, w2M, eM, 0, 0, 0);       \
    }

// Merged aggregation for pair slot rr: all 5 filters, deduped loads.
// bAL = local b (geom index), bA = global b (in* index).
#define AGGM(RR)                                                               \
    {                                                                          \
        const int bAL = b0L + q * 4 + (RR);                                    \
        const int bA  = hbase + bAL;                                           \
        const f32x4 gA = *(const f32x4*)&geomall[bAL][0];                      \
        const f32x4 gB = *(const f32x4*)&geomall[bAL][4];                      \
        const float i0A = in0[bA * CC + cw];                                   \
        const float* i1A = in1 + (bA * CC + cw) * 3;                           \
        const float x1A = i1A[0], y1A = i1A[1], z1A = i1A[2];                  \
        const float* i2A = in2 + (bA * CC + cw) * 5;                           \
        const float p0A = i2A[0], p1A = i2A[1], p2A = i2A[2];                  \
        const float p3A = i2A[3], p4A = i2A[4];                                \
        const float s0A = rF0[(RR)];                                           \
        a0  = fmaf(s0A, i0A, a0);                                              \
        a5  = fmaf(s0A, x1A, a5);                                              \
        a6  = fmaf(s0A, y1A, a6);                                              \
        a7  = fmaf(s0A, z1A, a7);                                              \
        a16 = fmaf(s0A, p0A, a16);                                             \
        a17 = fmaf(s0A, p1A, a17);                                             \
        a18 = fmaf(s0A, p2A, a18);                                             \
        a19 = fmaf(s0A, p3A, a19);                                             \
        a20 = fmaf(s0A, p4A, a20);                                             \
        const float t1A = rF1[(RR)] * i0A;                                     \
        a2  = fmaf(t1A, gA[0], a2);                                            \
        a3  = fmaf(t1A, gA[1], a3);                                            \
        a4  = fmaf(t1A, gA[2], a4);                                            \
        const float t2A = rF2[(RR)] * i0A;                                     \
        a11 = fmaf(t2A, gA[3], a11);                                           \
        a12 = fmaf(t2A, gB[0], a12);                                           \
        a13 = fmaf(t2A, gB[1], a13);                                           \
        a14 = fmaf(t2A, gB[2], a14);                                           \
        a15 = fmaf(t2A, gB[3], a15);                                           \
        const float dtA = fmaf(gA[2], z1A, fmaf(gA[1], y1A, gA[0] * x1A));     \
        a1  = fmaf(rF3[(RR)], dtA, a1);                                        \
        const float cxA = fmaf(gA[1], z1A, -(gA[2] * y1A));                    \
        const float cyA = fmaf(gA[2], x1A, -(gA[0] * z1A));                    \
        const float czA = fmaf(gA[0], y1A, -(gA[1] * x1A));                    \
        a8  = fmaf(rF4[(RR)], cxA, a8);                                        \
        a9  = fmaf(rF4[(RR)], cyA, a9);                                        \
        a10 = fmaf(rF4[(RR)], czA, a10);                                       \
    }

#define RED(CMP, V)                                                            \
    {                                                                          \
        float vR = (V);                                                        \
        vR += __shfl_down(vR, 32);                                             \
        vR += __shfl_down(vR, 16);                                             \
        if (lane < 16) red[(w * 21 + (CMP)) * 16 + ln] = vR;                   \
    }

__global__ __launch_bounds__(512, 3) void tfn_mfma(
    const float* __restrict__ in0,   // [N,C,1]
    const float* __restrict__ in1,   // [N,C,3]
    const float* __restrict__ in2,   // [N,C,5]
    const float* __restrict__ rbf,   // [N,N,32]
    const float* __restrict__ rij,   // [N,N,3]
    const float* __restrict__ w1_0, const float* __restrict__ b1_0,
    const float* __restrict__ w2_0, const float* __restrict__ b2_0,
    const float* __restrict__ w1_1, const float* __restrict__ b1_1,
    const float* __restrict__ w2_1, const float* __restrict__ b2_1,
    const float* __restrict__ w1_2, const float* __restrict__ b1_2,
    const float* __restrict__ w2_2, const float* __restrict__ b2_2,
    const float* __restrict__ w1_3, const float* __restrict__ b1_3,
    const float* __restrict__ w2_3, const float* __restrict__ b2_3,
    const float* __restrict__ w1_4, const float* __restrict__ b1_4,
    const float* __restrict__ w2_4, const float* __restrict__ b2_4,
    float* __restrict__ out)
{
    const int a     = blockIdx.x >> 1;
    const int hbase = (blockIdx.x & 1) * HB;   // this block's b half-range base
    const int tid  = threadIdx.x;
    const int w    = tid >> 6;     // wave 0..7 = (b-range pair) * 2 + channel-half
    const int lane = tid & 63;
    const int q    = lane >> 4;
    const int ln   = lane & 15;
    const int ch0  = (w & 1) * 16; // this wave's channel-half base
    const int cw   = ch0 + ln;     // this lane's channel

    __shared__ short wlds[5 * 2 * 32 * WS];  // 25600 B; aliased as `red` later
    __shared__ float geomall[HB][GS];        // 12288 B: this half's geometry
    __shared__ float b1lds[5 * 32];          // 640 B: layer-1 biases

    // staging indices; k2 = perm(k0): n-axis permutation for layer-2 weights
    const int n0 = tid >> 5, k0 = tid & 31;
    const int k2 = (k0 < 16) ? ((k0 >> 2) * 8 + (k0 & 3))
                             : (((k0 - 16) >> 2) * 8 + 4 + ((k0 - 16) & 3));

    STAGE_F(0, w1_0, w2_0)
    STAGE_F(1, w1_1, w2_1)
    STAGE_F(2, w1_2, w2_2)
    STAGE_F(3, w1_3, w2_3)
    STAGE_F(4, w1_4, w2_4)

    if (tid < 32) {
        b1lds[0 * 32 + tid] = b1_0[tid];
        b1lds[1 * 32 + tid] = b1_1[tid];
        b1lds[2 * 32 + tid] = b1_2[tid];
        b1lds[3 * 32 + tid] = b1_3[tid];
        b1lds[4 * 32 + tid] = b1_4[tid];
    }

    const size_t rowbase = (size_t)a * NN;
    const float Y2C = 0.28867513459481287f;  // 1/(2*sqrt(3))

    // ---- geometry for this half's 256 b's, one thread each ----
    if (tid < HB) {
        const float* rp = rij + (rowbase + hbase + tid) * 3;
        const float x = rp[0], y = rp[1], z = rp[2];
        const float d2 = x * x + y * y + z * z;
        const float d  = sqrtf(d2);
        const float m  = (d >= EPSF) ? 1.f : 0.f;
        const float inv = m / (d + EPSF);
        const float ir2 = m / fmaxf(d2, EPSF);
        f32x4 gA = { x * inv, y * inv, z * inv, x * y * ir2 };
        f32x4 gB = { y * z * ir2, (2.f * z * z - x * x - y * y) * (ir2 * Y2C),
                     z * x * ir2, (x * x - y * y) * (ir2 * 0.5f) };
        *(f32x4*)&geomall[tid][0] = gA;
        *(f32x4*)&geomall[tid][4] = gB;
    }

    // layer-2 bias: own channel only (5 VGPR)
    const float b2v0 = b2_0[cw], b2v1 = b2_1[cw], b2v2 = b2_2[cw];
    const float b2v3 = b2_3[cw], b2v4 = b2_4[cw];
    __syncthreads();

    // 21 named scalar accumulators
    float a0 = 0.f, a1 = 0.f, a2 = 0.f, a3 = 0.f, a4 = 0.f, a5 = 0.f, a6 = 0.f;
    float a7 = 0.f, a8 = 0.f, a9 = 0.f, a10 = 0.f, a11 = 0.f, a12 = 0.f, a13 = 0.f;
    float a14 = 0.f, a15 = 0.f, a16 = 0.f, a17 = 0.f, a18 = 0.f, a19 = 0.f, a20 = 0.f;

    const int pairbL = (w >> 1) * 64;        // this wave-pair's local b range
    const float* rbase = rbf + (rowbase + hbase + pairbL + ln) * 32 + q * 8;

    // software prefetch of the first rbf fragment
    f32x4 curA = *(const f32x4*)rbase;
    f32x4 curB = *(const f32x4*)(rbase + 4);

    #pragma unroll 1
    for (int t = 0; t < 4; ++t) {
        const int b0L = pairbL + t * 16;

        // convert current rbf fragment (packed), then prefetch next tile's
        union { bf16x8 v; unsigned u[4]; } ru;
        ru.u[0] = cvtpk(curA[0], curA[1]);
        ru.u[1] = cvtpk(curA[2], curA[3]);
        ru.u[2] = cvtpk(curB[0], curB[1]);
        ru.u[3] = cvtpk(curB[2], curB[3]);
        const bf16x8 rbfF = ru.v;
        if (t < 3) {
            curA = *(const f32x4*)(rbase + (t + 1) * 512);
            curB = *(const f32x4*)(rbase + (t + 1) * 512 + 4);
        }

        f32x4 rF0, rF1, rF2, rF3, rF4;
        MLP3S(0 * 64 * WS, 0 * 32, b2v0, rF0)
        MLP3S(1 * 64 * WS, 1 * 32, b2v1, rF1)
        MLP3S(2 * 64 * WS, 2 * 32, b2v2, rF2)
        MLP3S(3 * 64 * WS, 3 * 32, b2v3, rF3)
        MLP3S(4 * 64 * WS, 4 * 32, b2v4, rF4)

        AGGM(0) AGGM(1) AGGM(2) AGGM(3)
    }

    // ---- reduce over q within wave, then over the 4 wave-pairs via LDS ----
    __syncthreads();                       // all waves done reading wlds
    float* red = (float*)wlds;             // [8][21][16] = 10752 B <= 25600 B
    RED(0,  a0)  RED(1,  a1)  RED(2,  a2)  RED(3,  a3)  RED(4,  a4)
    RED(5,  a5)  RED(6,  a6)  RED(7,  a7)  RED(8,  a8)  RED(9,  a9)
    RED(10, a10) RED(11, a11) RED(12, a12) RED(13, a13) RED(14, a14)
    RED(15, a15) RED(16, a16) RED(17, a17) RED(18, a18) RED(19, a19)
    RED(20, a20)
    __syncthreads();

    const int NC = NN * CC;
    for (int e = tid; e < 21 * 32; e += 512) {
        const int cmp = e >> 5, c = e & 31;
        const int hh = c >> 4, l2 = c & 15;
        float s = 0.f;
        #pragma unroll
        for (int p = 0; p < 4; ++p)
            s += red[((p * 2 + hh) * 21 + cmp) * 16 + l2];
        int idx;
        if (cmp == 0)       idx = a * CC + c;                                       // o0_s
        else if (cmp == 1)  idx = NC + a * CC + c;                                  // o0_b
        else if (cmp < 5)   idx = 2 * NC + (a * CC + c) * 3 + (cmp - 2);            // o1_a
        else if (cmp < 8)   idx = 2 * NC + 3 * NC + (a * CC + c) * 3 + (cmp - 5);   // o1_s
        else if (cmp < 11)  idx = 2 * NC + 6 * NC + (a * CC + c) * 3 + (cmp - 8);   // o1_c
        else if (cmp < 16)  idx = 11 * NC + (a * CC + c) * 5 + (cmp - 11);          // o2_a
        else                idx = 11 * NC + 5 * NC + (a * CC + c) * 5 + (cmp - 16); // o2_s
        atomicAdd(&out[idx], s);   // two half-blocks per a combine here
    }
}

extern "C" void kernel_launch(void* const* d_in, const int* in_sizes, int n_in,
                              void* d_out, int out_size, void* d_ws, size_t ws_size,
                              hipStream_t stream) {
    const float* in0 = (const float*)d_in[0];
    const float* in1 = (const float*)d_in[1];
    const float* in2 = (const float*)d_in[2];
    const float* rbf = (const float*)d_in[3];
    const float* rij = (const float*)d_in[4];

    // deterministic: zero output, then both half-blocks atomically accumulate
    hipMemsetAsync(d_out, 0, (size_t)out_size * sizeof(float), stream);

    hipLaunchKernelGGL(tfn_mfma, dim3(NN * 2), dim3(512), 0, stream,
                       in0, in1, in2, rbf, rij,
                       (const float*)d_in[5],  (const float*)d_in[6],
                       (const float*)d_in[7],  (const float*)d_in[8],
                       (const float*)d_in[9],  (const float*)d_in[10],
                       (const float*)d_in[11], (const float*)d_in[12],
                       (const float*)d_in[13], (const float*)d_in[14],
                       (const float*)d_in[15], (const float*)d_in[16],
                       (const float*)d_in[17], (const float*)d_in[18],
                       (const float*)d_in[19], (const float*)d_in[20],
                       (const float*)d_in[21], (const float*)d_in[22],
                       (const float*)d_in[23], (const float*)d_in[24],
                       (float*)d_out);
}

// Round 20
// 37.734 us; speedup vs baseline: 2.7212x; 1.3258x over previous
//
#include <hip/hip_runtime.h>
#include <math.h>

#define NN 512
#define CC 32
#define EPSF 1e-8f
#define WS 40   // shorts per LDS weight row
#define GS 12   // floats per geom row (48 B: 2-way max bank aliasing = free)

typedef __attribute__((ext_vector_type(8))) short bf16x8;
typedef __attribute__((ext_vector_type(4))) float f32x4;

// packed f32x2 -> bf16x2 (RTNE), 1 VALU op; lo -> low 16 bits
__device__ __forceinline__ unsigned cvtpk(float lo, float hi) {
    unsigned r;
    asm("v_cvt_pk_bf16_f32 %0, %1, %2" : "=v"(r) : "v"(lo), "v"(hi));
    return r;
}

// Vectorized weight staging: waves 0-3 stage w1 (plain), waves 4-7 stage w2
// (k-axis permuted by perm so layer-2's A-frag is lane-local).  Per filter:
// one dwordx4 load + 2 cvt_pk + one ds_write_b64 per thread.
#define STAGE_F(F, W1P, W2P)                                                   \
    if (tid < 256) {                                                           \
        const f32x4 v_ = *(const f32x4*)((W1P) + tid * 4);                     \
        uint2 pk_ = { cvtpk(v_[0], v_[1]), cvtpk(v_[2], v_[3]) };              \
        *(uint2*)&wlds[(((F) * 2 + 0) * 32 + sn) * WS + sk] = pk_;             \
    } else {                                                                   \
        const f32x4 v_ = *(const f32x4*)((W2P) + (tid - 256) * 4);             \
        uint2 pk_ = { cvtpk(v_[0], v_[1]), cvtpk(v_[2], v_[3]) };              \
        *(uint2*)&wlds[(((F) * 2 + 1) * 32 + sn) * WS + sk2] = pk_;            \
    }

// Radial MLP, transpose-free (w2 fragment pre-hoisted to registers):
//  layer1 swapped: d = mfma(w1, rbf) -> lane(q,ln) = h[n][p=ln]
//  relu+cvt_pk packs the 8 lane-local h values -> layer-2 A-frag (w2 permuted)
//  layer2: R[rr] = rad[p=4q+rr][cw]
#define MLP3S(WOFF, B1LO, B1HI, B2V, W2F, R)                                       \
    {                                                                              \
        const bf16x8 w1loM = *(const bf16x8*)&wlds[(WOFF) + ln * WS + q * 8];      \
        const bf16x8 w1hiM = *(const bf16x8*)&wlds[(WOFF) + (16 + ln) * WS + q * 8]; \
        f32x4 d0M = (B1LO);                                                        \
        f32x4 d1M = (B1HI);                                                        \
        d0M = __builtin_amdgcn_mfma_f32_16x16x32_bf16(w1loM, rbfF, d0M, 0, 0, 0);  \
        d1M = __builtin_amdgcn_mfma_f32_16x16x32_bf16(w1hiM, rbfF, d1M, 0, 0, 0);  \
        union { bf16x8 v; unsigned u[4]; } hu;                                     \
        hu.u[0] = cvtpk(fmaxf(d0M[0], 0.f), fmaxf(d0M[1], 0.f));                   \
        hu.u[1] = cvtpk(fmaxf(d0M[2], 0.f), fmaxf(d0M[3], 0.f));                   \
        hu.u[2] = cvtpk(fmaxf(d1M[0], 0.f), fmaxf(d1M[1], 0.f));                   \
        hu.u[3] = cvtpk(fmaxf(d1M[2], 0.f), fmaxf(d1M[3], 0.f));                   \
        f32x4 eM = { (B2V), (B2V), (B2V), (B2V) };                                 \
        R = __builtin_amdgcn_mfma_f32_16x16x32_bf16(hu.v, (W2F), eM, 0, 0, 0);     \
    }

// Merged aggregation for pair slot rr: all 5 filters; loads via per-tile base
// pointers + compile-time immediate offsets (no per-slot address math).
#define AGGM(RR)                                                               \
    {                                                                          \
        const f32x4 gA = *(const f32x4*)&gbase[goff + (RR) * GS];              \
        const f32x4 gB = *(const f32x4*)&gbase[goff + (RR) * GS + 4];          \
        const float i0A = p0[(RR) * 32];                                       \
        const float x1A = p1[(RR) * 96 + 0];                                   \
        const float y1A = p1[(RR) * 96 + 1];                                   \
        const float z1A = p1[(RR) * 96 + 2];                                   \
        const float p0A = p2[(RR) * 160 + 0];                                  \
        const float p1A = p2[(RR) * 160 + 1];                                  \
        const float p2A = p2[(RR) * 160 + 2];                                  \
        const float p3A = p2[(RR) * 160 + 3];                                  \
        const float p4A = p2[(RR) * 160 + 4];                                  \
        const float s0A = rF0[(RR)];                                           \
        a0  = fmaf(s0A, i0A, a0);                                              \
        a5  = fmaf(s0A, x1A, a5);                                              \
        a6  = fmaf(s0A, y1A, a6);                                              \
        a7  = fmaf(s0A, z1A, a7);                                              \
        a16 = fmaf(s0A, p0A, a16);                                             \
        a17 = fmaf(s0A, p1A, a17);                                             \
        a18 = fmaf(s0A, p2A, a18);                                             \
        a19 = fmaf(s0A, p3A, a19);                                             \
        a20 = fmaf(s0A, p4A, a20);                                             \
        const float t1A = rF1[(RR)] * i0A;                                     \
        a2  = fmaf(t1A, gA[0], a2);                                            \
        a3  = fmaf(t1A, gA[1], a3);                                            \
        a4  = fmaf(t1A, gA[2], a4);                                            \
        const float t2A = rF2[(RR)] * i0A;                                     \
        a11 = fmaf(t2A, gA[3], a11);                                           \
        a12 = fmaf(t2A, gB[0], a12);                                           \
        a13 = fmaf(t2A, gB[1], a13);                                           \
        a14 = fmaf(t2A, gB[2], a14);                                           \
        a15 = fmaf(t2A, gB[3], a15);                                           \
        const float dtA = fmaf(gA[2], z1A, fmaf(gA[1], y1A, gA[0] * x1A));     \
        a1  = fmaf(rF3[(RR)], dtA, a1);                                        \
        const float cxA = fmaf(gA[1], z1A, -(gA[2] * y1A));                    \
        const float cyA = fmaf(gA[2], x1A, -(gA[0] * z1A));                    \
        const float czA = fmaf(gA[0], y1A, -(gA[1] * x1A));                    \
        a8  = fmaf(rF4[(RR)], cxA, a8);                                        \
        a9  = fmaf(rF4[(RR)], cyA, a9);                                        \
        a10 = fmaf(rF4[(RR)], czA, a10);                                       \
    }

#define RED(CMP, V)                                                            \
    {                                                                          \
        float vR = (V);                                                        \
        vR += __shfl_down(vR, 32);                                             \
        vR += __shfl_down(vR, 16);                                             \
        if (lane < 16) red[(w * 21 + (CMP)) * 16 + ln] = vR;                   \
    }

__global__ __launch_bounds__(512, 2) void tfn_mfma(
    const float* __restrict__ in0,   // [N,C,1]
    const float* __restrict__ in1,   // [N,C,3]
    const float* __restrict__ in2,   // [N,C,5]
    const float* __restrict__ rbf,   // [N,N,32]
    const float* __restrict__ rij,   // [N,N,3]
    const float* __restrict__ w1_0, const float* __restrict__ b1_0,
    const float* __restrict__ w2_0, const float* __restrict__ b2_0,
    const float* __restrict__ w1_1, const float* __restrict__ b1_1,
    const float* __restrict__ w2_1, const float* __restrict__ b2_1,
    const float* __restrict__ w1_2, const float* __restrict__ b1_2,
    const float* __restrict__ w2_2, const float* __restrict__ b2_2,
    const float* __restrict__ w1_3, const float* __restrict__ b1_3,
    const float* __restrict__ w2_3, const float* __restrict__ b2_3,
    const float* __restrict__ w1_4, const float* __restrict__ b1_4,
    const float* __restrict__ w2_4, const float* __restrict__ b2_4,
    float* __restrict__ out)
{
    const int a    = blockIdx.x;
    const int tid  = threadIdx.x;
    const int w    = tid >> 6;     // wave 0..7 = (b-range pair) * 2 + channel-half
    const int lane = tid & 63;
    const int q    = lane >> 4;
    const int ln   = lane & 15;
    const int ch0  = (w & 1) * 16; // this wave's channel-half base
    const int cw   = ch0 + ln;     // this lane's channel

    __shared__ short wlds[5 * 2 * 32 * WS];  // 25600 B; aliased as `red` later
    __shared__ float geomall[NN][GS];        // 24576 B: all b's geometry (mask folded)

    // staging indices (vectorized): threads <256 handle w1, >=256 handle w2.
    const int su  = (tid < 256) ? tid : (tid - 256);
    const int sn  = su >> 3;            // row n 0..31
    const int sk0 = (su & 7) * 4;       // 4-aligned column base
    const int sk  = sk0;                // w1: plain
    const int sk2 = (sk0 < 16) ? ((sk0 >> 2) * 8)
                               : (((sk0 - 16) >> 2) * 8 + 4);  // w2: permuted base

    STAGE_F(0, w1_0, w2_0)
    STAGE_F(1, w1_1, w2_1)
    STAGE_F(2, w1_2, w2_2)
    STAGE_F(3, w1_3, w2_3)
    STAGE_F(4, w1_4, w2_4)

    const size_t rowbase = (size_t)a * NN;
    const float Y2C = 0.28867513459481287f;  // 1/(2*sqrt(3))

    // ---- geometry for ALL 512 b's, one thread each ----
    {
        const float* rp = rij + (rowbase + tid) * 3;
        const float x = rp[0], y = rp[1], z = rp[2];
        const float d2 = x * x + y * y + z * z;
        const float d  = sqrtf(d2);
        const float m  = (d >= EPSF) ? 1.f : 0.f;
        const float inv = m / (d + EPSF);
        const float ir2 = m / fmaxf(d2, EPSF);
        f32x4 gA = { x * inv, y * inv, z * inv, x * y * ir2 };
        f32x4 gB = { y * z * ir2, (2.f * z * z - x * x - y * y) * (ir2 * Y2C),
                     z * x * ir2, (x * x - y * y) * (ir2 * 0.5f) };
        *(f32x4*)&geomall[tid][0] = gA;
        *(f32x4*)&geomall[tid][4] = gB;
    }

    // layer-1 bias C-in vectors (regs); layer-2 bias: own channel only
    const f32x4 b1lo0 = *(const f32x4*)(b1_0 + 4 * q), b1hi0 = *(const f32x4*)(b1_0 + 16 + 4 * q);
    const f32x4 b1lo1 = *(const f32x4*)(b1_1 + 4 * q), b1hi1 = *(const f32x4*)(b1_1 + 16 + 4 * q);
    const f32x4 b1lo2 = *(const f32x4*)(b1_2 + 4 * q), b1hi2 = *(const f32x4*)(b1_2 + 16 + 4 * q);
    const f32x4 b1lo3 = *(const f32x4*)(b1_3 + 4 * q), b1hi3 = *(const f32x4*)(b1_3 + 16 + 4 * q);
    const f32x4 b1lo4 = *(const f32x4*)(b1_4 + 4 * q), b1hi4 = *(const f32x4*)(b1_4 + 16 + 4 * q);
    const float b2v0 = b2_0[cw], b2v1 = b2_1[cw], b2v2 = b2_2[cw];
    const float b2v3 = b2_3[cw], b2v4 = b2_4[cw];
    __syncthreads();

    // hoist loop-invariant layer-2 weight fragments into registers (20 VGPR)
    const bf16x8 w2F0 = *(const bf16x8*)&wlds[0 * 64 * WS + (32 + ch0 + ln) * WS + q * 8];
    const bf16x8 w2F1 = *(const bf16x8*)&wlds[1 * 64 * WS + (32 + ch0 + ln) * WS + q * 8];
    const bf16x8 w2F2 = *(const bf16x8*)&wlds[2 * 64 * WS + (32 + ch0 + ln) * WS + q * 8];
    const bf16x8 w2F3 = *(const bf16x8*)&wlds[3 * 64 * WS + (32 + ch0 + ln) * WS + q * 8];
    const bf16x8 w2F4 = *(const bf16x8*)&wlds[4 * 64 * WS + (32 + ch0 + ln) * WS + q * 8];

    // 21 named scalar accumulators
    float a0 = 0.f, a1 = 0.f, a2 = 0.f, a3 = 0.f, a4 = 0.f, a5 = 0.f, a6 = 0.f;
    float a7 = 0.f, a8 = 0.f, a9 = 0.f, a10 = 0.f, a11 = 0.f, a12 = 0.f, a13 = 0.f;
    float a14 = 0.f, a15 = 0.f, a16 = 0.f, a17 = 0.f, a18 = 0.f, a19 = 0.f, a20 = 0.f;

    const int pairb = (w >> 1) * 128;        // this wave-pair's b range
    const int pbase = pairb + q * 4;         // this lane's pair-slot base

    // per-tile base pointers (advance by constants; AGGM offsets are immediates)
    const float* p0 = in0 + pbase * CC + cw;
    const float* p1 = in1 + (pbase * CC + cw) * 3;
    const float* p2 = in2 + (pbase * CC + cw) * 5;
    const float* gbase = (const float*)geomall;
    int goff = pbase * GS;

    // software prefetch of the first rbf fragment
    const float* rbase = rbf + (rowbase + pairb + ln) * 32 + q * 8;
    f32x4 curA = *(const f32x4*)rbase;
    f32x4 curB = *(const f32x4*)(rbase + 4);

    #pragma unroll 1
    for (int t = 0; t < 8; ++t) {
        // convert current rbf fragment (packed), then prefetch next tile's
        union { bf16x8 v; unsigned u[4]; } ru;
        ru.u[0] = cvtpk(curA[0], curA[1]);
        ru.u[1] = cvtpk(curA[2], curA[3]);
        ru.u[2] = cvtpk(curB[0], curB[1]);
        ru.u[3] = cvtpk(curB[2], curB[3]);
        const bf16x8 rbfF = ru.v;
        if (t < 7) {
            curA = *(const f32x4*)(rbase + (t + 1) * 512);
            curB = *(const f32x4*)(rbase + (t + 1) * 512 + 4);
        }

        f32x4 rF0, rF1, rF2, rF3, rF4;
        MLP3S(0 * 64 * WS, b1lo0, b1hi0, b2v0, w2F0, rF0)
        MLP3S(1 * 64 * WS, b1lo1, b1hi1, b2v1, w2F1, rF1)
        MLP3S(2 * 64 * WS, b1lo2, b1hi2, b2v2, w2F2, rF2)
        MLP3S(3 * 64 * WS, b1lo3, b1hi3, b2v3, w2F3, rF3)
        MLP3S(4 * 64 * WS, b1lo4, b1hi4, b2v4, w2F4, rF4)

        AGGM(0) AGGM(1) AGGM(2) AGGM(3)

        p0 += 16 * CC;
        p1 += 16 * CC * 3;
        p2 += 16 * CC * 5;
        goff += 16 * GS;
    }

    // ---- reduce over q within wave, then over the 4 b-range pairs via LDS ----
    __syncthreads();                       // all waves done reading wlds
    float* red = (float*)wlds;             // [8][21][16] = 10752 B <= 25600 B
    RED(0,  a0)  RED(1,  a1)  RED(2,  a2)  RED(3,  a3)  RED(4,  a4)
    RED(5,  a5)  RED(6,  a6)  RED(7,  a7)  RED(8,  a8)  RED(9,  a9)
    RED(10, a10) RED(11, a11) RED(12, a12) RED(13, a13) RED(14, a14)
    RED(15, a15) RED(16, a16) RED(17, a17) RED(18, a18) RED(19, a19)
    RED(20, a20)
    __syncthreads();

    const int NC = NN * CC;
    for (int e = tid; e < 21 * 32; e += 512) {
        const int cmp = e >> 5, c = e & 31;
        const int hh = c >> 4, l2 = c & 15;
        float s = 0.f;
        #pragma unroll
        for (int p = 0; p < 4; ++p)
            s += red[((p * 2 + hh) * 21 + cmp) * 16 + l2];
        int idx;
        if (cmp == 0)       idx = a * CC + c;                                       // o0_s
        else if (cmp == 1)  idx = NC + a * CC + c;                                  // o0_b
        else if (cmp < 5)   idx = 2 * NC + (a * CC + c) * 3 + (cmp - 2);            // o1_a
        else if (cmp < 8)   idx = 2 * NC + 3 * NC + (a * CC + c) * 3 + (cmp - 5);   // o1_s
        else if (cmp < 11)  idx = 2 * NC + 6 * NC + (a * CC + c) * 3 + (cmp - 8);   // o1_c
        else if (cmp < 16)  idx = 11 * NC + (a * CC + c) * 5 + (cmp - 11);          // o2_a
        else                idx = 11 * NC + 5 * NC + (a * CC + c) * 5 + (cmp - 16); // o2_s
        out[idx] = s;
    }
}

extern "C" void kernel_launch(void* const* d_in, const int* in_sizes, int n_in,
                              void* d_out, int out_size, void* d_ws, size_t ws_size,
                              hipStream_t stream) {
    const float* in0 = (const float*)d_in[0];
    const float* in1 = (const float*)d_in[1];
    const float* in2 = (const float*)d_in[2];
    const float* rbf = (const float*)d_in[3];
    const float* rij = (const float*)d_in[4];

    hipLaunchKernelGGL(tfn_mfma, dim3(NN), dim3(512), 0, stream,
                       in0, in1, in2, rbf, rij,
                       (const float*)d_in[5],  (const float*)d_in[6],
                       (const float*)d_in[7],  (const float*)d_in[8],
                       (const float*)d_in[9],  (const float*)d_in[10],
                       (const float*)d_in[11], (const float*)d_in[12],
                       (const float*)d_in[13], (const float*)d_in[14],
                       (const float*)d_in[15], (const float*)d_in[16],
                       (const float*)d_in[17], (const float*)d_in[18],
                       (const float*)d_in[19], (const float*)d_in[20],
                       (const float*)d_in[21], (const float*)d_in[22],
                       (const float*)d_in[23], (const float*)d_in[24],
                       (float*)d_out);
}